// Round 12
// baseline (109.004 us; speedup 1.0000x reference)
//
#include <hip/hip_runtime.h>
#include <cstdint>
#include <cstddef>

#define HH 256
#define WW 256
#define HWW (HH * WW)

typedef __attribute__((ext_vector_type(8))) short bf16x8;
typedef __attribute__((ext_vector_type(4))) float f32x4;

__device__ inline unsigned short f2bf(float f) {
  unsigned u = __float_as_uint(f);
  unsigned r = (u + 0x7fffu + ((u >> 16) & 1u)) >> 16;
  return (unsigned short)r;
}
__device__ inline float bf2f(unsigned short u) {
  return __uint_as_float((unsigned)u << 16);
}
__device__ inline float bf_lo(unsigned w) { return __uint_as_float(w << 16); }
__device__ inline float bf_hi(unsigned w) { return __uint_as_float(w & 0xffff0000u); }

// ---------------------------------------------------------------------------
// Weight repack descriptors (mode 0: gate [cin][9]; mode 1: deform [k][c][o];
// mode 2: MFMA A-fragment pack bf16, K-order = tap*CIN + c).
// ---------------------------------------------------------------------------
struct RD { const float* src; void* dst; int cin, cout, mode; };
struct RA { RD d[9]; };

__device__ void repack_one(const RD& t) {
  if (t.mode == 2) {
    const int NST = (t.cin * 9 + 31) / 32;
    const int OT = (t.cout + 15) / 16;
    const int n = OT * NST * 512;
    unsigned short* dst = (unsigned short*)t.dst;
    for (int i = threadIdx.x; i < n; i += 256) {
      int j = i & 7;
      int l = (i >> 3) & 63;
      int rest = i >> 9;
      int s = rest % NST;
      int ot = rest / NST;
      int o = ot * 16 + (l & 15);
      int klin = s * 32 + ((l >> 4) << 3) + j;
      int tap = klin / t.cin;
      int c = klin % t.cin;
      float v = 0.f;
      if (tap < 9 && o < t.cout) v = t.src[(o * t.cin + c) * 9 + tap];
      dst[i] = f2bf(v);
    }
  } else {
    float* dst = (float*)t.dst;
    const int n = t.cin * t.cout * 9;
    for (int i = threadIdx.x; i < n; i += 256) {
      int k = i % 9;
      int rest = i / 9;
      int c = rest % t.cin;
      int o = rest / t.cin;
      if (t.mode == 0) dst[(c * 9 + k) * t.cout + o] = t.src[(o * t.cin + c) * 9 + k];
      else             dst[(k * t.cin + c) * t.cout + o] = t.src[(o * t.cin + c) * 9 + k];
    }
  }
}

// ---------------------------------------------------------------------------
// Prep: blocks 0..255 convert f_E/f_F fp32 NCHW -> bf16 NHWC; block 256 of
// each z runs 3 weight repacks.
// ---------------------------------------------------------------------------
__global__ __launch_bounds__(256) void prep_k(
    RA ra, const float* __restrict__ fe, const float* __restrict__ ff,
    unsigned short* __restrict__ xe, unsigned short* __restrict__ xf) {
  const int b = blockIdx.z;
  if (blockIdx.x == 256) {
    const int d0 = b * 3;
    for (int d = d0; d < d0 + 3 && d < 9; ++d) repack_one(ra.d[d]);
    return;
  }
  const int pixel = blockIdx.x * 256 + threadIdx.x;
#pragma unroll
  for (int t = 0; t < 2; ++t) {
    const float* src = t ? ff : fe;
    unsigned short* dst = t ? xf : xe;
    unsigned w[8];
#pragma unroll
    for (int j = 0; j < 8; ++j) {
      unsigned short lo = f2bf(src[((size_t)b * 16 + 2 * j) * HWW + pixel]);
      unsigned short hi = f2bf(src[((size_t)b * 16 + 2 * j + 1) * HWW + pixel]);
      w[j] = (unsigned)lo | ((unsigned)hi << 16);
    }
    uint4* d4 = (uint4*)(dst + ((size_t)b * HWW + pixel) * 16);
    d4[0] = make_uint4(w[0], w[1], w[2], w[3]);
    d4[1] = make_uint4(w[4], w[5], w[6], w[7]);
  }
}

// ---------------------------------------------------------------------------
// Fused K1+K4: two CIN=32 convs over one staged input cat(XE,XF). 32x8 tile.
// ---------------------------------------------------------------------------
__global__ __launch_bounds__(256) void conv_dual_k(
    const unsigned short* __restrict__ inA, const unsigned short* __restrict__ inB,
    const unsigned short* __restrict__ w1, const float* __restrict__ b1,
    const unsigned short* __restrict__ w2, const float* __restrict__ b2,
    unsigned short* __restrict__ out1, unsigned short* __restrict__ out2) {
  constexpr int NSLOT = 4, NST = 9, SHIFT = 1, STRIDE = 64, PX = 34, PY = 10;
  __shared__ __align__(16) char smem[PY * PX * STRIDE];

  const int b = blockIdx.z;
  const int tx0 = blockIdx.x * 32;
  const int ty0 = blockIdx.y * 8;
  const int tid = threadIdx.x;
  const int lane = tid & 63;
  const int wv = tid >> 6;

  bf16x8 afr1[NST], afr2[NST];
#pragma unroll
  for (int s = 0; s < NST; ++s) {
    afr1[s] = *(const bf16x8*)(w1 + (size_t)((s * 64 + lane) * 8));
    afr2[s] = *(const bf16x8*)(w2 + (size_t)((s * 64 + lane) * 8));
  }

  const int px_l = lane & 15;
  const int og = lane >> 4;

  f32x4 acc1[4], acc2[4];
  {
    f32x4 bv1, bv2;
#pragma unroll
    for (int r = 0; r < 4; ++r) {
      bv1[r] = b1[og * 4 + r];
      bv2[r] = b2[og * 4 + r];
    }
#pragma unroll
    for (int t = 0; t < 4; ++t) { acc1[t] = bv1; acc2[t] = bv2; }
  }

  for (int i = tid; i < PY * PX * NSLOT; i += 256) {
    int pp = i / NSLOT;
    int s = i - pp * NSLOT;
    int ly = pp / PX;
    int lx = pp - ly * PX;
    int gy = ty0 + ly - 1;
    int gx = tx0 + lx - 1;
    uint4 v = make_uint4(0, 0, 0, 0);
    if (gy >= 0 && gy < HH && gx >= 0 && gx < WW) {
      const unsigned short* src = (s < 2) ? inA : inB;
      int sl = (s >= 2) ? s - 2 : s;
      v = *(const uint4*)(src + ((size_t)b * HWW + (size_t)gy * WW + gx) * 16 + sl * 8);
    }
    int swz = (s ^ (pp >> SHIFT)) & 3;
    *(uint4*)(smem + (size_t)pp * STRIDE + (swz << 4)) = v;
  }
  __syncthreads();

  int dpix[NST], dslot[NST];
#pragma unroll
  for (int s = 0; s < NST; ++s) {
    int klin = s * 32 + og * 8;
    int tap = klin / 32;
    int coff = klin % 32;
    dpix[s] = (tap / 3) * PX + (tap % 3);
    dslot[s] = coff >> 3;
  }

  const int oy_l = wv * 2;
#pragma unroll
  for (int t = 0; t < 4; ++t) {
    const int base_pix = (oy_l + (t >> 1)) * PX + (t & 1) * 16 + px_l;
#pragma unroll
    for (int s = 0; s < NST; ++s) {
      int pp = base_pix + dpix[s];
      int off = pp * STRIDE + (((dslot[s] ^ (pp >> SHIFT)) & 3) << 4);
      bf16x8 bvv = *(const bf16x8*)(smem + off);
      acc1[t] = __builtin_amdgcn_mfma_f32_16x16x32_bf16(afr1[s], bvv, acc1[t], 0, 0, 0);
      acc2[t] = __builtin_amdgcn_mfma_f32_16x16x32_bf16(afr2[s], bvv, acc2[t], 0, 0, 0);
    }
  }

#pragma unroll
  for (int t = 0; t < 4; ++t) {
    const int gy = ty0 + oy_l + (t >> 1);
    const int gx = tx0 + (t & 1) * 16 + px_l;
    const size_t base = ((size_t)b * HWW + (size_t)gy * WW + gx) * 16 + og * 4;
    {
      unsigned lo = (unsigned)f2bf(fmaxf(acc1[t][0], 0.f)) |
                    ((unsigned)f2bf(fmaxf(acc1[t][1], 0.f)) << 16);
      unsigned hi = (unsigned)f2bf(fmaxf(acc1[t][2], 0.f)) |
                    ((unsigned)f2bf(fmaxf(acc1[t][3], 0.f)) << 16);
      *(uint2*)(out1 + base) = make_uint2(lo, hi);
    }
    {
      unsigned lo = (unsigned)f2bf(fmaxf(acc2[t][0], 0.f)) |
                    ((unsigned)f2bf(fmaxf(acc2[t][1], 0.f)) << 16);
      unsigned hi = (unsigned)f2bf(fmaxf(acc2[t][2], 0.f)) |
                    ((unsigned)f2bf(fmaxf(acc2[t][3], 0.f)) << 16);
      *(uint2*)(out2 + base) = make_uint2(lo, hi);
    }
  }
}

// ---------------------------------------------------------------------------
// Fat-merged mid kernel: even blocks run sagate (K2+K3), odd blocks run
// om_fused (K5+K6). om output now padded NHWC [pixel][32] bf16.
// ---------------------------------------------------------------------------
__global__ __launch_bounds__(256) void mid_k(
    const unsigned short* __restrict__ xa, const unsigned short* __restrict__ xe,
    const unsigned short* __restrict__ xf,
    const float* __restrict__ gw, const float* __restrict__ gb,
    const unsigned short* __restrict__ wrm, const float* __restrict__ rb,
    unsigned short* __restrict__ x2out,
    const unsigned short* __restrict__ xt,
    const unsigned short* __restrict__ w2m, const float* __restrict__ b2,
    const unsigned short* __restrict__ w3m, const float* __restrict__ b3,
    unsigned short* __restrict__ omb) {
  __shared__ __align__(16) char smem[24704];   // max(21760 sagate, 24704 om)

  const int flat = blockIdx.x;
  const int half = flat & 1;
  const int rem = flat >> 1;            // 0..1023
  const int b = rem >> 8;
  const int ty0 = ((rem >> 3) & 31) * 8;
  const int tx0 = (rem & 7) * 32;
  const int tid = threadIdx.x;
  const int lane = tid & 63;
  const int wv = tid >> 6;
  const int px_l = lane & 15;
  const int og = lane >> 4;

  if (half == 0) {
    // ================= sagate =================
    constexpr int NST = 9, SHIFT = 1, STRIDE = 64, PX = 34, PY = 10;
    bf16x8 afr[NST];
#pragma unroll
    for (int s = 0; s < NST; ++s)
      afr[s] = *(const bf16x8*)(wrm + (size_t)((s * 64 + lane) * 8));

    f32x4 acc[4];
    {
      f32x4 bv;
#pragma unroll
      for (int r = 0; r < 4; ++r) bv[r] = rb[og * 4 + r];
#pragma unroll
      for (int t = 0; t < 4; ++t) acc[t] = bv;
    }

    for (int i = tid; i < PY * PX * 2; i += 256) {
      int pp = i >> 1;
      int s = 2 + (i & 1);
      int ly = pp / PX;
      int lx = pp - ly * PX;
      int gy = ty0 + ly - 1;
      int gx = tx0 + lx - 1;
      uint4 v = make_uint4(0, 0, 0, 0);
      if (gy >= 0 && gy < HH && gx >= 0 && gx < WW)
        v = *(const uint4*)(xf + ((size_t)b * HWW + (size_t)gy * WW + gx) * 16 + (s - 2) * 8);
      int swz = (s ^ (pp >> SHIFT)) & 3;
      *(uint4*)(smem + (size_t)pp * STRIDE + (swz << 4)) = v;
    }

    const float gbias = gb[0];
    for (int i = tid; i < PY * PX; i += 256) {
      int ly = i / PX;
      int lx = i - ly * PX;
      int gy = ty0 + ly - 1;
      int gx = tx0 + lx - 1;
      uint4 v0 = make_uint4(0, 0, 0, 0), v1 = make_uint4(0, 0, 0, 0);
      if (gy >= 0 && gy < HH && gx >= 0 && gx < WW) {
        float a = gbias;
#pragma unroll
        for (int ky = 0; ky < 3; ++ky) {
          int ay = gy + ky - 1;
          if (ay < 0 || ay >= HH) continue;
#pragma unroll
          for (int kx = 0; kx < 3; ++kx) {
            int ax = gx + kx - 1;
            if (ax < 0 || ax >= WW) continue;
            const int k = ky * 3 + kx;
            const uint4* p = (const uint4*)(xa + ((size_t)b * HWW + (size_t)ay * WW + ax) * 16);
            uint4 t0 = p[0], t1 = p[1];
            unsigned wv8[8] = {t0.x, t0.y, t0.z, t0.w, t1.x, t1.y, t1.z, t1.w};
#pragma unroll
            for (int j = 0; j < 8; ++j) {
              a = fmaf(bf_lo(wv8[j]), gw[(2 * j) * 9 + k], a);
              a = fmaf(bf_hi(wv8[j]), gw[(2 * j + 1) * 9 + k], a);
            }
          }
        }
        float m = 1.0f / (1.0f + expf(-a));
        const uint4* pe = (const uint4*)(xe + ((size_t)b * HWW + (size_t)gy * WW + gx) * 16);
        uint4 e0 = pe[0], e1 = pe[1];
        unsigned ev[8] = {e0.x, e0.y, e0.z, e0.w, e1.x, e1.y, e1.z, e1.w};
        unsigned r[8];
#pragma unroll
        for (int j = 0; j < 8; ++j) {
          unsigned short lo = f2bf(bf_lo(ev[j]) * m);
          unsigned short hi = f2bf(bf_hi(ev[j]) * m);
          r[j] = (unsigned)lo | ((unsigned)hi << 16);
        }
        v0 = make_uint4(r[0], r[1], r[2], r[3]);
        v1 = make_uint4(r[4], r[5], r[6], r[7]);
      }
      int swz0 = (0 ^ (i >> SHIFT)) & 3;
      int swz1 = (1 ^ (i >> SHIFT)) & 3;
      *(uint4*)(smem + (size_t)i * STRIDE + (swz0 << 4)) = v0;
      *(uint4*)(smem + (size_t)i * STRIDE + (swz1 << 4)) = v1;
    }
    __syncthreads();

    int dpix[NST], dslot[NST];
#pragma unroll
    for (int s = 0; s < NST; ++s) {
      int klin = s * 32 + og * 8;
      int tap = klin / 32;
      int coff = klin % 32;
      dpix[s] = (tap / 3) * PX + (tap % 3);
      dslot[s] = coff >> 3;
    }

    const int oy_l = wv * 2;
#pragma unroll
    for (int t = 0; t < 4; ++t) {
      const int base_pix = (oy_l + (t >> 1)) * PX + (t & 1) * 16 + px_l;
#pragma unroll
      for (int s = 0; s < NST; ++s) {
        int pp = base_pix + dpix[s];
        int off = pp * STRIDE + (((dslot[s] ^ (pp >> SHIFT)) & 3) << 4);
        bf16x8 bvv = *(const bf16x8*)(smem + off);
        acc[t] = __builtin_amdgcn_mfma_f32_16x16x32_bf16(afr[s], bvv, acc[t], 0, 0, 0);
      }
    }

#pragma unroll
    for (int t = 0; t < 4; ++t) {
      const int gy = ty0 + oy_l + (t >> 1);
      const int gx = tx0 + (t & 1) * 16 + px_l;
      unsigned lo = (unsigned)f2bf(fmaxf(acc[t][0], 0.f)) |
                    ((unsigned)f2bf(fmaxf(acc[t][1], 0.f)) << 16);
      unsigned hi = (unsigned)f2bf(fmaxf(acc[t][2], 0.f)) |
                    ((unsigned)f2bf(fmaxf(acc[t][3], 0.f)) << 16);
      *(uint2*)(x2out + ((size_t)b * HWW + (size_t)gy * WW + gx) * 16 + og * 4) = make_uint2(lo, hi);
    }
  } else {
    // ================= om_fused =================
    char* stage = smem;                   // om_t2 [12][36], 32B/px
    char* t3 = smem + 12 * 36 * 32;       // om_t3 [10][34], 32B/px

    for (int i = tid; i < 12 * 36 * 2; i += 256) {
      int pp = i >> 1;
      int s = i & 1;
      int lr = pp / 36;
      int lc = pp - lr * 36;
      int gy = ty0 + lr - 2;
      int gx = tx0 + lc - 2;
      uint4 v = make_uint4(0, 0, 0, 0);
      if (gy >= 0 && gy < HH && gx >= 0 && gx < WW)
        v = *(const uint4*)(xt + ((size_t)b * HWW + (size_t)gy * WW + gx) * 16 + s * 8);
      int swz = (s ^ (pp >> 2)) & 1;
      *(uint4*)(stage + (size_t)pp * 32 + (swz << 4)) = v;
    }
    __syncthreads();

    {
      bf16x8 afr1[5];
#pragma unroll
      for (int s = 0; s < 5; ++s)
        afr1[s] = *(const bf16x8*)(w2m + (size_t)((s * 64 + lane) * 8));
      f32x4 bvec;
#pragma unroll
      for (int r = 0; r < 4; ++r) bvec[r] = b2[og * 4 + r];
      int tap1[5], slot1[5];
#pragma unroll
      for (int s = 0; s < 5; ++s) {
        int klin = s * 32 + og * 8;
        int tap = klin / 16;
        if (tap > 8) tap = 8;
        int coff = klin % 16;
        tap1[s] = (tap / 3) * 36 + (tap % 3);
        slot1[s] = coff >> 3;
      }
      for (int f = wv; f < 22; f += 4) {
        int p = f * 16 + px_l;
        int r = p / 34;
        int c = p - r * 34;
        f32x4 acc = bvec;
#pragma unroll
        for (int s = 0; s < 5; ++s) {
          int pp2 = r * 36 + c + tap1[s];
          int off = pp2 * 32 + (((slot1[s] ^ (pp2 >> 2)) & 1) << 4);
          bf16x8 bv = *(const bf16x8*)(stage + off);
          acc = __builtin_amdgcn_mfma_f32_16x16x32_bf16(afr1[s], bv, acc, 0, 0, 0);
        }
        if (p < 340) {
          int gy = ty0 + r - 1;
          int gx = tx0 + c - 1;
          unsigned lo = 0, hi = 0;
          if (gy >= 0 && gy < HH && gx >= 0 && gx < WW) {  // zero-pad halo
            lo = (unsigned)f2bf(fmaxf(acc[0], 0.f)) | ((unsigned)f2bf(fmaxf(acc[1], 0.f)) << 16);
            hi = (unsigned)f2bf(fmaxf(acc[2], 0.f)) | ((unsigned)f2bf(fmaxf(acc[3], 0.f)) << 16);
          }
          int slot = og >> 1;
          int off = p * 32 + (((slot ^ (p >> 2)) & 1) << 4) + (og & 1) * 8;
          *(uint2*)(t3 + off) = make_uint2(lo, hi);
        }
      }
    }
    __syncthreads();

    bf16x8 afr2[2][5];
#pragma unroll
    for (int ot = 0; ot < 2; ++ot)
#pragma unroll
      for (int s = 0; s < 5; ++s)
        afr2[ot][s] = *(const bf16x8*)(w3m + (size_t)(((ot * 5 + s) * 64 + lane) * 8));

    f32x4 acc2[4][2];
#pragma unroll
    for (int ot = 0; ot < 2; ++ot) {
      f32x4 bv;
#pragma unroll
      for (int r = 0; r < 4; ++r) {
        int o = ot * 16 + og * 4 + r;
        bv[r] = b3[o < 27 ? o : 26];
      }
#pragma unroll
      for (int t = 0; t < 4; ++t) acc2[t][ot] = bv;
    }

    int tap2[5], slot2[5];
#pragma unroll
    for (int s = 0; s < 5; ++s) {
      int klin = s * 32 + og * 8;
      int tap = klin / 16;
      if (tap > 8) tap = 8;
      int coff = klin % 16;
      tap2[s] = (tap / 3) * 34 + (tap % 3);
      slot2[s] = coff >> 3;
    }

    const int oy_l = wv * 2;
#pragma unroll
    for (int t = 0; t < 4; ++t) {
      const int base_pix = (oy_l + (t >> 1)) * 34 + (t & 1) * 16 + px_l;
#pragma unroll
      for (int s = 0; s < 5; ++s) {
        int pp = base_pix + tap2[s];
        int off = pp * 32 + (((slot2[s] ^ (pp >> 2)) & 1) << 4);
        bf16x8 bv = *(const bf16x8*)(t3 + off);
        acc2[t][0] = __builtin_amdgcn_mfma_f32_16x16x32_bf16(afr2[0][s], bv, acc2[t][0], 0, 0, 0);
        acc2[t][1] = __builtin_amdgcn_mfma_f32_16x16x32_bf16(afr2[1][s], bv, acc2[t][1], 0, 0, 0);
      }
    }

    // Epilogue: om raw, padded NHWC [pixel][32] bf16 (o=27..31 pad).
#pragma unroll
    for (int t = 0; t < 4; ++t) {
      const int gy = ty0 + oy_l + (t >> 1);
      const int gx = tx0 + (t & 1) * 16 + px_l;
      unsigned short* dst = omb + ((size_t)b * HWW + (size_t)gy * WW + gx) * 32;
#pragma unroll
      for (int ot = 0; ot < 2; ++ot) {
        const int o0 = ot * 16 + og * 4;
        unsigned lo = (unsigned)f2bf(acc2[t][ot][0]) | ((unsigned)f2bf(acc2[t][ot][1]) << 16);
        unsigned hi = (unsigned)f2bf(acc2[t][ot][2]) | ((unsigned)f2bf(acc2[t][ot][3]) << 16);
        *(uint2*)(dst + o0) = make_uint2(lo, hi);
      }
    }
  }
}

// ---------------------------------------------------------------------------
// Modulated deformable conv v6: om in padded NHWC [pixel][32] bf16 (4 vector
// loads); phase A precomputes all 9 taps' bilinear weights/addresses into
// registers; phase B gathers+FMAs (tap k+1 gathers overlap tap k FMAs).
// __launch_bounds__(256,4): VGPR cap 128 for load ILP. Math order identical
// to deform_v4 (k outer, c inner).
// ---------------------------------------------------------------------------
__global__ __launch_bounds__(256, 4) void deform_v6(
    const unsigned short* __restrict__ xn, const unsigned short* __restrict__ om32,
    const float* __restrict__ wt, const float* __restrict__ bias,
    unsigned short* __restrict__ out) {
  const int bid = blockIdx.x;
  const int xcd = bid & 7;
  const int b = xcd >> 1;
  const int pb = ((bid >> 3) << 1) | (xcd & 1);
  const int pixel = pb * 256 + (int)threadIdx.x;
  const int y = pixel >> 8;
  const int xq = pixel & 255;
  const unsigned short* xb = xn + (size_t)b * HWW * 16;

  // om: 27 values, 4 coalesced uint4 loads
  const uint4* omp = (const uint4*)(om32 + ((size_t)b * HWW + pixel) * 32);
  uint4 q0 = omp[0], q1 = omp[1], q2 = omp[2], q3 = omp[3];
  unsigned ow[14] = {q0.x, q0.y, q0.z, q0.w, q1.x, q1.y, q1.z, q1.w,
                     q2.x, q2.y, q2.z, q2.w, q3.x, q3.y};

  // phase A: per-tap bilinear weights + clamped corner indices
  int i00[9], i01[9], i10[9], i11[9];
  float w00[9], w01[9], w10[9], w11[9];
#pragma unroll
  for (int k = 0; k < 9; ++k) {
    unsigned wy_ = ow[(2 * k) >> 1];
    float offy = ((2 * k) & 1) ? bf_hi(wy_) : bf_lo(wy_);
    unsigned wx_ = ow[(2 * k + 1) >> 1];
    float offx = ((2 * k + 1) & 1) ? bf_hi(wx_) : bf_lo(wx_);
    unsigned wm_ = ow[(18 + k) >> 1];
    float mr = ((18 + k) & 1) ? bf_hi(wm_) : bf_lo(wm_);
    float m = 1.0f / (1.0f + expf(-mr));
    float py = (float)y + (float)(k / 3 - 1) + offy;
    float px = (float)xq + (float)(k % 3 - 1) + offx;
    float y0f = floorf(py);
    float x0f = floorf(px);
    float dy = py - y0f;
    float dx = px - x0f;
    int y0 = (int)y0f, x0 = (int)x0f;
    int y1 = y0 + 1, x1 = x0 + 1;
    bool vy0 = (y0 >= 0) && (y0 < HH);
    bool vy1 = (y1 >= 0) && (y1 < HH);
    bool vx0 = (x0 >= 0) && (x0 < WW);
    bool vx1 = (x1 >= 0) && (x1 < WW);
    int yc0 = min(max(y0, 0), HH - 1);
    int yc1 = min(max(y1, 0), HH - 1);
    int xc0 = min(max(x0, 0), WW - 1);
    int xc1 = min(max(x1, 0), WW - 1);
    float a00 = (1.f - dy) * (1.f - dx) * m;
    float a01 = (1.f - dy) * dx * m;
    float a10 = dy * (1.f - dx) * m;
    float a11 = dy * dx * m;
    if (!(vy0 && vx0)) a00 = 0.f;
    if (!(vy0 && vx1)) a01 = 0.f;
    if (!(vy1 && vx0)) a10 = 0.f;
    if (!(vy1 && vx1)) a11 = 0.f;
    w00[k] = a00; w01[k] = a01; w10[k] = a10; w11[k] = a11;
    i00[k] = yc0 * WW + xc0;
    i01[k] = yc0 * WW + xc1;
    i10[k] = yc1 * WW + xc0;
    i11[k] = yc1 * WW + xc1;
  }

  float acc[16];
#pragma unroll
  for (int o = 0; o < 16; ++o) acc[o] = bias[o];

  // phase B: gathers + FMAs (independent across k; compiler can pipeline)
#pragma unroll
  for (int k = 0; k < 9; ++k) {
    const uint4* p00 = (const uint4*)(xb + (size_t)i00[k] * 16);
    const uint4* p01 = (const uint4*)(xb + (size_t)i01[k] * 16);
    const uint4* p10 = (const uint4*)(xb + (size_t)i10[k] * 16);
    const uint4* p11 = (const uint4*)(xb + (size_t)i11[k] * 16);
    uint4 a0 = p00[0], a1 = p00[1];
    uint4 b0 = p01[0], b1 = p01[1];
    uint4 c0 = p10[0], c1 = p10[1];
    uint4 d0 = p11[0], d1 = p11[1];
    unsigned wA[8] = {a0.x, a0.y, a0.z, a0.w, a1.x, a1.y, a1.z, a1.w};
    unsigned wB[8] = {b0.x, b0.y, b0.z, b0.w, b1.x, b1.y, b1.z, b1.w};
    unsigned wC[8] = {c0.x, c0.y, c0.z, c0.w, c1.x, c1.y, c1.z, c1.w};
    unsigned wD[8] = {d0.x, d0.y, d0.z, d0.w, d1.x, d1.y, d1.z, d1.w};

    float s[16];
#pragma unroll
    for (int j = 0; j < 8; ++j) {
      s[2 * j]     = bf_lo(wA[j]) * w00[k] + bf_lo(wB[j]) * w01[k] + bf_lo(wC[j]) * w10[k] + bf_lo(wD[j]) * w11[k];
      s[2 * j + 1] = bf_hi(wA[j]) * w00[k] + bf_hi(wB[j]) * w01[k] + bf_hi(wC[j]) * w10[k] + bf_hi(wD[j]) * w11[k];
    }
    const float* wk = wt + (size_t)k * 256;
#pragma unroll
    for (int c = 0; c < 16; ++c)
#pragma unroll
      for (int o = 0; o < 16; ++o)
        acc[o] = fmaf(s[c], wk[c * 16 + o], acc[o]);
  }
  unsigned r[8];
#pragma unroll
  for (int j = 0; j < 8; ++j) {
    unsigned short lo = f2bf(fmaxf(acc[2 * j], 0.f));
    unsigned short hi = f2bf(fmaxf(acc[2 * j + 1], 0.f));
    r[j] = (unsigned)lo | ((unsigned)hi << 16);
  }
  uint4* d4 = (uint4*)(out + ((size_t)b * HWW + pixel) * 16);
  d4[0] = make_uint4(r[0], r[1], r[2], r[3]);
  d4[1] = make_uint4(r[4], r[5], r[6], r[7]);
}

// ---------------------------------------------------------------------------
// Fused K8+K9 (fin_fused): unchanged from round 9.
// ---------------------------------------------------------------------------
__global__ __launch_bounds__(256) void fin_fused_k(
    const unsigned short* __restrict__ xsa, const unsigned short* __restrict__ xf,
    const unsigned short* __restrict__ wdm, const float* __restrict__ bd,
    const unsigned short* __restrict__ x2,
    const unsigned short* __restrict__ wfm, const float* __restrict__ bfv,
    float* __restrict__ outp) {
  __shared__ __align__(16) char smem[12 * 36 * 64 + 10 * 34 * 32];
  char* stage = smem;
  char* dtile = smem + 12 * 36 * 64;
  char* x2tile = smem;

  const int b = blockIdx.z;
  const int tx0 = blockIdx.x * 32;
  const int ty0 = blockIdx.y * 8;
  const int tid = threadIdx.x;
  const int lane = tid & 63;
  const int wv = tid >> 6;
  const int px_l = lane & 15;
  const int og = lane >> 4;

  for (int i = tid; i < 12 * 36 * 4; i += 256) {
    int pp = i >> 2;
    int s = i & 3;
    int lr = pp / 36;
    int lc = pp - lr * 36;
    int gy = ty0 + lr - 2;
    int gx = tx0 + lc - 2;
    uint4 v = make_uint4(0, 0, 0, 0);
    if (gy >= 0 && gy < HH && gx >= 0 && gx < WW) {
      const unsigned short* src = (s < 2) ? xsa : xf;
      int sl = (s >= 2) ? s - 2 : s;
      v = *(const uint4*)(src + ((size_t)b * HWW + (size_t)gy * WW + gx) * 16 + sl * 8);
    }
    int swz = (s ^ (pp >> 1)) & 3;
    *(uint4*)(stage + (size_t)pp * 64 + (swz << 4)) = v;
  }
  __syncthreads();

  {
    bf16x8 afr1[9];
#pragma unroll
    for (int s = 0; s < 9; ++s)
      afr1[s] = *(const bf16x8*)(wdm + (size_t)((s * 64 + lane) * 8));
    f32x4 bvec;
#pragma unroll
    for (int r = 0; r < 4; ++r) bvec[r] = bd[og * 4 + r];
    int tap1[9], slot1[9];
#pragma unroll
    for (int s = 0; s < 9; ++s) {
      int klin = s * 32 + og * 8;
      int tap = klin / 32;
      int coff = klin % 32;
      tap1[s] = (tap / 3) * 36 + (tap % 3);
      slot1[s] = coff >> 3;
    }
    for (int f = wv; f < 22; f += 4) {
      int p = f * 16 + px_l;
      int r = p / 34;
      int c = p - r * 34;
      f32x4 acc = bvec;
#pragma unroll
      for (int s = 0; s < 9; ++s) {
        int pp2 = r * 36 + c + tap1[s];
        int off = pp2 * 64 + (((slot1[s] ^ (pp2 >> 1)) & 3) << 4);
        bf16x8 bv = *(const bf16x8*)(stage + off);
        acc = __builtin_amdgcn_mfma_f32_16x16x32_bf16(afr1[s], bv, acc, 0, 0, 0);
      }
      if (p < 340) {
        int gy = ty0 + r - 1;
        int gx = tx0 + c - 1;
        unsigned lo = 0, hi = 0;
        if (gy >= 0 && gy < HH && gx >= 0 && gx < WW) {
          lo = (unsigned)f2bf(fmaxf(acc[0], 0.f)) | ((unsigned)f2bf(fmaxf(acc[1], 0.f)) << 16);
          hi = (unsigned)f2bf(fmaxf(acc[2], 0.f)) | ((unsigned)f2bf(fmaxf(acc[3], 0.f)) << 16);
        }
        int slot = og >> 1;
        int off = p * 32 + (((slot ^ (p >> 2)) & 1) << 4) + (og & 1) * 8;
        *(uint2*)(dtile + off) = make_uint2(lo, hi);
      }
    }
  }
  __syncthreads();

  for (int i = tid; i < 340 * 2; i += 256) {
    int pp = i >> 1;
    int s = i & 1;
    int r = pp / 34;
    int c = pp - r * 34;
    int gy = ty0 + r - 1;
    int gx = tx0 + c - 1;
    uint4 v = make_uint4(0, 0, 0, 0);
    if (gy >= 0 && gy < HH && gx >= 0 && gx < WW)
      v = *(const uint4*)(x2 + ((size_t)b * HWW + (size_t)gy * WW + gx) * 16 + s * 8);
    int swz = (s ^ (pp >> 2)) & 1;
    *(uint4*)(x2tile + (size_t)pp * 32 + (swz << 4)) = v;
  }
  __syncthreads();

  bf16x8 afr2[9];
#pragma unroll
  for (int s = 0; s < 9; ++s)
    afr2[s] = *(const bf16x8*)(wfm + (size_t)((s * 64 + lane) * 8));

  f32x4 acc2[4];
  {
    f32x4 bv;
#pragma unroll
    for (int r = 0; r < 4; ++r) bv[r] = bfv[og * 4 + r];
#pragma unroll
    for (int t = 0; t < 4; ++t) acc2[t] = bv;
  }

  int tap2[9], slot2[9];
#pragma unroll
  for (int s = 0; s < 9; ++s) {
    int klin = s * 32 + og * 8;
    int tap = klin / 32;
    int coff = klin % 32;
    tap2[s] = (tap / 3) * 34 + (tap % 3);
    slot2[s] = coff >> 3;
  }

  const int oy_l = wv * 2;
#pragma unroll
  for (int t = 0; t < 4; ++t) {
    const int base_pix = (oy_l + (t >> 1)) * 34 + (t & 1) * 16 + px_l;
#pragma unroll
    for (int s = 0; s < 9; ++s) {
      int pp = base_pix + tap2[s];
      const char* basep = (slot2[s] < 2) ? x2tile : dtile;
      int sl = slot2[s] & 1;
      int off = pp * 32 + (((sl ^ (pp >> 2)) & 1) << 4);
      bf16x8 bv = *(const bf16x8*)(basep + off);
      acc2[t] = __builtin_amdgcn_mfma_f32_16x16x32_bf16(afr2[s], bv, acc2[t], 0, 0, 0);
    }
  }

#pragma unroll
  for (int t = 0; t < 4; ++t) {
    const int gy = ty0 + oy_l + (t >> 1);
    const int gx = tx0 + (t & 1) * 16 + px_l;
    const int o0 = og * 4;
#pragma unroll
    for (int r = 0; r < 4; ++r)
      outp[((size_t)b * 16 + o0 + r) * HWW + (size_t)gy * WW + gx] = fmaxf(acc2[t][r], 0.f);
  }
}

extern "C" void kernel_launch(void* const* d_in, const int* in_sizes, int n_in,
                              void* d_out, int out_size, void* d_ws, size_t ws_size,
                              hipStream_t stream) {
  (void)in_sizes; (void)n_in; (void)out_size; (void)ws_size;
  const float* f_E = (const float*)d_in[0];
  const float* f_F = (const float*)d_in[1];
  const float* att_w1 = (const float*)d_in[2];
  const float* att_b1 = (const float*)d_in[3];
  const float* att_w2 = (const float*)d_in[4];
  const float* att_b2 = (const float*)d_in[5];
  const float* ref_w = (const float*)d_in[6];
  const float* ref_b = (const float*)d_in[7];
  const float* om_w1 = (const float*)d_in[8];
  const float* om_b1 = (const float*)d_in[9];
  const float* om_w2 = (const float*)d_in[10];
  const float* om_b2 = (const float*)d_in[11];
  const float* om_w3 = (const float*)d_in[12];
  const float* om_b3 = (const float*)d_in[13];
  const float* dcb_w = (const float*)d_in[14];
  const float* dcb_b = (const float*)d_in[15];
  const float* dcbref_w = (const float*)d_in[16];
  const float* dcbref_b = (const float*)d_in[17];
  const float* fin_w = (const float*)d_in[18];
  const float* fin_b = (const float*)d_in[19];
  float* outp = (float*)d_out;

  const size_t TN = (size_t)4 * HWW * 16;            // bf16 NHWC tensor elems
  unsigned short* XE  = (unsigned short*)d_ws;       // f_E
  unsigned short* XF  = XE + TN;                     // f_F
  unsigned short* XA  = XF + TN;                     // conv_a
  unsigned short* XT  = XA + TN;                     // om_t2
  unsigned short* X2  = XT + TN;                     // f_EFsa
  unsigned short* XSA = X2 + TN;                     // f_Edc
  unsigned short* OMB = XSA + TN;                    // om bf16 NHWC [pixel][32]
  unsigned short* WM  = OMB + (size_t)4 * HWW * 32;

  unsigned short* WM_att1 = WM;                 // CIN32 OT1: 4608 ush
  unsigned short* WM_ref  = WM_att1 + 4608;
  unsigned short* WM_om1  = WM_ref + 4608;
  unsigned short* WM_om2  = WM_om1 + 4608;      // CIN16 OT1: 2560
  unsigned short* WM_om3  = WM_om2 + 2560;      // CIN16 OT2: 5120
  unsigned short* WM_dref = WM_om3 + 5120;
  unsigned short* WM_fin  = WM_dref + 4608;
  float* WF_att2 = (float*)(WM_fin + 4608);     // mode0: 144 f
  float* WF_dcb  = WF_att2 + 144;               // mode1: 2304 f

  RA ra;
  ra.d[0] = {att_w1, WM_att1, 32, 16, 2};
  ra.d[1] = {ref_w, WM_ref, 32, 16, 2};
  ra.d[2] = {om_w1, WM_om1, 32, 16, 2};
  ra.d[3] = {om_w2, WM_om2, 16, 16, 2};
  ra.d[4] = {om_w3, WM_om3, 16, 27, 2};
  ra.d[5] = {dcbref_w, WM_dref, 32, 16, 2};
  ra.d[6] = {fin_w, WM_fin, 32, 16, 2};
  ra.d[7] = {att_w2, WF_att2, 16, 1, 0};
  ra.d[8] = {dcb_w, WF_dcb, 16, 16, 1};

  dim3 blk(256);
  prep_k<<<dim3(257, 1, 4), blk, 0, stream>>>(ra, f_E, f_F, XE, XF);

  dim3 gm(WW / 32, HH / 8, 4);   // 1024 blocks

  // K1+K4: conv_a, om_t2
  conv_dual_k<<<gm, blk, 0, stream>>>(XE, XF, WM_att1, att_b1, WM_om1, om_b1, XA, XT);
  // K2+K3 (even blocks) || K5+K6 (odd blocks); om -> padded NHWC
  mid_k<<<dim3(2048), blk, 0, stream>>>(XA, XE, XF, WF_att2, att_b2, WM_ref, ref_b, X2,
                                        XT, WM_om2, om_b2, WM_om3, om_b3, OMB);
  // K7: f_Edc (ILP-restructured deform)
  deform_v6<<<dim3(1024), blk, 0, stream>>>(XE, OMB, WF_dcb, dcb_b, XSA);
  // K8+K9: out
  fin_fused_k<<<gm, blk, 0, stream>>>(XSA, XF, WM_dref, dcbref_b, X2, WM_fin, fin_b, outp);
}

// Round 13
// 108.199 us; speedup vs baseline: 1.0074x; 1.0074x over previous
//
#include <hip/hip_runtime.h>
#include <cstdint>
#include <cstddef>

#define HH 256
#define WW 256
#define HWW (HH * WW)

typedef __attribute__((ext_vector_type(8))) short bf16x8;
typedef __attribute__((ext_vector_type(4))) float f32x4;

__device__ inline unsigned short f2bf(float f) {
  unsigned u = __float_as_uint(f);
  unsigned r = (u + 0x7fffu + ((u >> 16) & 1u)) >> 16;
  return (unsigned short)r;
}
__device__ inline float bf2f(unsigned short u) {
  return __uint_as_float((unsigned)u << 16);
}
__device__ inline float bf_lo(unsigned w) { return __uint_as_float(w << 16); }
__device__ inline float bf_hi(unsigned w) { return __uint_as_float(w & 0xffff0000u); }

// ---------------------------------------------------------------------------
// Weight repack (standalone, 9 blocks). mode 0: gate [cin][9]; mode 1: deform
// [k][c][o]; mode 2: MFMA A-fragment pack bf16, K-order = tap*CIN + c.
// ---------------------------------------------------------------------------
struct RD { const float* src; void* dst; int cin, cout, mode; };
struct RA { RD d[9]; };

__global__ __launch_bounds__(256) void repack_k(RA a) {
  const RD t = a.d[blockIdx.x];
  if (t.mode == 2) {
    const int NST = (t.cin * 9 + 31) / 32;
    const int OT = (t.cout + 15) / 16;
    const int n = OT * NST * 512;
    unsigned short* dst = (unsigned short*)t.dst;
    for (int i = threadIdx.x; i < n; i += 256) {
      int j = i & 7;
      int l = (i >> 3) & 63;
      int rest = i >> 9;
      int s = rest % NST;
      int ot = rest / NST;
      int o = ot * 16 + (l & 15);
      int klin = s * 32 + ((l >> 4) << 3) + j;
      int tap = klin / t.cin;
      int c = klin % t.cin;
      float v = 0.f;
      if (tap < 9 && o < t.cout) v = t.src[(o * t.cin + c) * 9 + tap];
      dst[i] = f2bf(v);
    }
  } else {
    float* dst = (float*)t.dst;
    const int n = t.cin * t.cout * 9;
    for (int i = threadIdx.x; i < n; i += 256) {
      int k = i % 9;
      int rest = i / 9;
      int c = rest % t.cin;
      int o = rest / t.cin;
      if (t.mode == 0) dst[(c * 9 + k) * t.cout + o] = t.src[(o * t.cin + c) * 9 + k];
      else             dst[(k * t.cin + c) * t.cout + o] = t.src[(o * t.cin + c) * 9 + k];
    }
  }
}

// ---------------------------------------------------------------------------
// Fused prep+K1+K4 (conv_dual2): reads f_E/f_F fp32 NCHW directly; converts
// to bf16 during staging (1 px/thread, coalesced per channel plane); writes
// the XE/XF bf16 NHWC interiors as a side effect; then two CIN=32 MFMA convs
// over the staged tile -> conv_a, om_t2. 32x8 tile, 1024 blocks.
// ---------------------------------------------------------------------------
__global__ __launch_bounds__(256) void conv_dual2_k(
    const float* __restrict__ fe, const float* __restrict__ ff,
    const unsigned short* __restrict__ w1, const float* __restrict__ b1,
    const unsigned short* __restrict__ w2, const float* __restrict__ b2,
    unsigned short* __restrict__ xe, unsigned short* __restrict__ xf,
    unsigned short* __restrict__ out1, unsigned short* __restrict__ out2) {
  constexpr int NST = 9, SHIFT = 1, STRIDE = 64, PX = 34, PY = 10;
  __shared__ __align__(16) char smem[PY * PX * STRIDE];

  const int b = blockIdx.z;
  const int tx0 = blockIdx.x * 32;
  const int ty0 = blockIdx.y * 8;
  const int tid = threadIdx.x;
  const int lane = tid & 63;
  const int wv = tid >> 6;

  bf16x8 afr1[NST], afr2[NST];
#pragma unroll
  for (int s = 0; s < NST; ++s) {
    afr1[s] = *(const bf16x8*)(w1 + (size_t)((s * 64 + lane) * 8));
    afr2[s] = *(const bf16x8*)(w2 + (size_t)((s * 64 + lane) * 8));
  }

  const int px_l = lane & 15;
  const int og = lane >> 4;

  f32x4 acc1[4], acc2[4];
  {
    f32x4 bv1, bv2;
#pragma unroll
    for (int r = 0; r < 4; ++r) {
      bv1[r] = b1[og * 4 + r];
      bv2[r] = b2[og * 4 + r];
    }
#pragma unroll
    for (int t = 0; t < 4; ++t) { acc1[t] = bv1; acc2[t] = bv2; }
  }

  // staging: one pixel per thread iteration; fp32 NCHW -> bf16, LDS + global
  for (int pp = tid; pp < PY * PX; pp += 256) {
    int ly = pp / PX;
    int lx = pp - ly * PX;
    int gy = ty0 + ly - 1;
    int gx = tx0 + lx - 1;
    bool in = (gy >= 0) && (gy < HH) && (gx >= 0) && (gx < WW);
    bool interior = (ly >= 1) && (ly <= 8) && (lx >= 1) && (lx <= 32);
    const size_t pix = (size_t)b * 16 * HWW + (size_t)gy * WW + gx;
#pragma unroll
    for (int t = 0; t < 2; ++t) {
      const float* src = t ? ff : fe;
      unsigned w[8];
      if (in) {
#pragma unroll
        for (int j = 0; j < 8; ++j) {
          unsigned short lo = f2bf(src[pix + (size_t)(2 * j) * HWW]);
          unsigned short hi = f2bf(src[pix + (size_t)(2 * j + 1) * HWW]);
          w[j] = (unsigned)lo | ((unsigned)hi << 16);
        }
      } else {
#pragma unroll
        for (int j = 0; j < 8; ++j) w[j] = 0;
      }
      uint4 v0 = make_uint4(w[0], w[1], w[2], w[3]);
      uint4 v1 = make_uint4(w[4], w[5], w[6], w[7]);
      int s0 = t * 2;
      int swz0 = (s0 ^ (pp >> SHIFT)) & 3;
      int swz1 = ((s0 + 1) ^ (pp >> SHIFT)) & 3;
      *(uint4*)(smem + (size_t)pp * STRIDE + (swz0 << 4)) = v0;
      *(uint4*)(smem + (size_t)pp * STRIDE + (swz1 << 4)) = v1;
      if (interior) {
        unsigned short* dst = (t ? xf : xe) + ((size_t)b * HWW + (size_t)gy * WW + gx) * 16;
        uint4* d4 = (uint4*)dst;
        d4[0] = v0;
        d4[1] = v1;
      }
    }
  }
  __syncthreads();

  int dpix[NST], dslot[NST];
#pragma unroll
  for (int s = 0; s < NST; ++s) {
    int klin = s * 32 + og * 8;
    int tap = klin / 32;
    int coff = klin % 32;
    dpix[s] = (tap / 3) * PX + (tap % 3);
    dslot[s] = coff >> 3;
  }

  const int oy_l = wv * 2;
#pragma unroll
  for (int t = 0; t < 4; ++t) {
    const int base_pix = (oy_l + (t >> 1)) * PX + (t & 1) * 16 + px_l;
#pragma unroll
    for (int s = 0; s < NST; ++s) {
      int pp = base_pix + dpix[s];
      int off = pp * STRIDE + (((dslot[s] ^ (pp >> SHIFT)) & 3) << 4);
      bf16x8 bvv = *(const bf16x8*)(smem + off);
      acc1[t] = __builtin_amdgcn_mfma_f32_16x16x32_bf16(afr1[s], bvv, acc1[t], 0, 0, 0);
      acc2[t] = __builtin_amdgcn_mfma_f32_16x16x32_bf16(afr2[s], bvv, acc2[t], 0, 0, 0);
    }
  }

#pragma unroll
  for (int t = 0; t < 4; ++t) {
    const int gy = ty0 + oy_l + (t >> 1);
    const int gx = tx0 + (t & 1) * 16 + px_l;
    const size_t base = ((size_t)b * HWW + (size_t)gy * WW + gx) * 16 + og * 4;
    {
      unsigned lo = (unsigned)f2bf(fmaxf(acc1[t][0], 0.f)) |
                    ((unsigned)f2bf(fmaxf(acc1[t][1], 0.f)) << 16);
      unsigned hi = (unsigned)f2bf(fmaxf(acc1[t][2], 0.f)) |
                    ((unsigned)f2bf(fmaxf(acc1[t][3], 0.f)) << 16);
      *(uint2*)(out1 + base) = make_uint2(lo, hi);
    }
    {
      unsigned lo = (unsigned)f2bf(fmaxf(acc2[t][0], 0.f)) |
                    ((unsigned)f2bf(fmaxf(acc2[t][1], 0.f)) << 16);
      unsigned hi = (unsigned)f2bf(fmaxf(acc2[t][2], 0.f)) |
                    ((unsigned)f2bf(fmaxf(acc2[t][3], 0.f)) << 16);
      *(uint2*)(out2 + base) = make_uint2(lo, hi);
    }
  }
}

// ---------------------------------------------------------------------------
// Fat-merged mid kernel: even blocks sagate (K2+K3), odd blocks om_fused
// (K5+K6). om output padded NHWC [pixel][32] bf16. (unchanged from round 12)
// ---------------------------------------------------------------------------
__global__ __launch_bounds__(256) void mid_k(
    const unsigned short* __restrict__ xa, const unsigned short* __restrict__ xe,
    const unsigned short* __restrict__ xf,
    const float* __restrict__ gw, const float* __restrict__ gb,
    const unsigned short* __restrict__ wrm, const float* __restrict__ rb,
    unsigned short* __restrict__ x2out,
    const unsigned short* __restrict__ xt,
    const unsigned short* __restrict__ w2m, const float* __restrict__ b2,
    const unsigned short* __restrict__ w3m, const float* __restrict__ b3,
    unsigned short* __restrict__ omb) {
  __shared__ __align__(16) char smem[24704];

  const int flat = blockIdx.x;
  const int half = flat & 1;
  const int rem = flat >> 1;
  const int b = rem >> 8;
  const int ty0 = ((rem >> 3) & 31) * 8;
  const int tx0 = (rem & 7) * 32;
  const int tid = threadIdx.x;
  const int lane = tid & 63;
  const int wv = tid >> 6;
  const int px_l = lane & 15;
  const int og = lane >> 4;

  if (half == 0) {
    constexpr int NST = 9, SHIFT = 1, STRIDE = 64, PX = 34, PY = 10;
    bf16x8 afr[NST];
#pragma unroll
    for (int s = 0; s < NST; ++s)
      afr[s] = *(const bf16x8*)(wrm + (size_t)((s * 64 + lane) * 8));

    f32x4 acc[4];
    {
      f32x4 bv;
#pragma unroll
      for (int r = 0; r < 4; ++r) bv[r] = rb[og * 4 + r];
#pragma unroll
      for (int t = 0; t < 4; ++t) acc[t] = bv;
    }

    for (int i = tid; i < PY * PX * 2; i += 256) {
      int pp = i >> 1;
      int s = 2 + (i & 1);
      int ly = pp / PX;
      int lx = pp - ly * PX;
      int gy = ty0 + ly - 1;
      int gx = tx0 + lx - 1;
      uint4 v = make_uint4(0, 0, 0, 0);
      if (gy >= 0 && gy < HH && gx >= 0 && gx < WW)
        v = *(const uint4*)(xf + ((size_t)b * HWW + (size_t)gy * WW + gx) * 16 + (s - 2) * 8);
      int swz = (s ^ (pp >> SHIFT)) & 3;
      *(uint4*)(smem + (size_t)pp * STRIDE + (swz << 4)) = v;
    }

    const float gbias = gb[0];
    for (int i = tid; i < PY * PX; i += 256) {
      int ly = i / PX;
      int lx = i - ly * PX;
      int gy = ty0 + ly - 1;
      int gx = tx0 + lx - 1;
      uint4 v0 = make_uint4(0, 0, 0, 0), v1 = make_uint4(0, 0, 0, 0);
      if (gy >= 0 && gy < HH && gx >= 0 && gx < WW) {
        float a = gbias;
#pragma unroll
        for (int ky = 0; ky < 3; ++ky) {
          int ay = gy + ky - 1;
          if (ay < 0 || ay >= HH) continue;
#pragma unroll
          for (int kx = 0; kx < 3; ++kx) {
            int ax = gx + kx - 1;
            if (ax < 0 || ax >= WW) continue;
            const int k = ky * 3 + kx;
            const uint4* p = (const uint4*)(xa + ((size_t)b * HWW + (size_t)ay * WW + ax) * 16);
            uint4 t0 = p[0], t1 = p[1];
            unsigned wv8[8] = {t0.x, t0.y, t0.z, t0.w, t1.x, t1.y, t1.z, t1.w};
#pragma unroll
            for (int j = 0; j < 8; ++j) {
              a = fmaf(bf_lo(wv8[j]), gw[(2 * j) * 9 + k], a);
              a = fmaf(bf_hi(wv8[j]), gw[(2 * j + 1) * 9 + k], a);
            }
          }
        }
        float m = 1.0f / (1.0f + expf(-a));
        const uint4* pe = (const uint4*)(xe + ((size_t)b * HWW + (size_t)gy * WW + gx) * 16);
        uint4 e0 = pe[0], e1 = pe[1];
        unsigned ev[8] = {e0.x, e0.y, e0.z, e0.w, e1.x, e1.y, e1.z, e1.w};
        unsigned r[8];
#pragma unroll
        for (int j = 0; j < 8; ++j) {
          unsigned short lo = f2bf(bf_lo(ev[j]) * m);
          unsigned short hi = f2bf(bf_hi(ev[j]) * m);
          r[j] = (unsigned)lo | ((unsigned)hi << 16);
        }
        v0 = make_uint4(r[0], r[1], r[2], r[3]);
        v1 = make_uint4(r[4], r[5], r[6], r[7]);
      }
      int swz0 = (0 ^ (i >> SHIFT)) & 3;
      int swz1 = (1 ^ (i >> SHIFT)) & 3;
      *(uint4*)(smem + (size_t)i * STRIDE + (swz0 << 4)) = v0;
      *(uint4*)(smem + (size_t)i * STRIDE + (swz1 << 4)) = v1;
    }
    __syncthreads();

    int dpix[NST], dslot[NST];
#pragma unroll
    for (int s = 0; s < NST; ++s) {
      int klin = s * 32 + og * 8;
      int tap = klin / 32;
      int coff = klin % 32;
      dpix[s] = (tap / 3) * PX + (tap % 3);
      dslot[s] = coff >> 3;
    }

    const int oy_l = wv * 2;
#pragma unroll
    for (int t = 0; t < 4; ++t) {
      const int base_pix = (oy_l + (t >> 1)) * PX + (t & 1) * 16 + px_l;
#pragma unroll
      for (int s = 0; s < NST; ++s) {
        int pp = base_pix + dpix[s];
        int off = pp * STRIDE + (((dslot[s] ^ (pp >> SHIFT)) & 3) << 4);
        bf16x8 bvv = *(const bf16x8*)(smem + off);
        acc[t] = __builtin_amdgcn_mfma_f32_16x16x32_bf16(afr[s], bvv, acc[t], 0, 0, 0);
      }
    }

#pragma unroll
    for (int t = 0; t < 4; ++t) {
      const int gy = ty0 + oy_l + (t >> 1);
      const int gx = tx0 + (t & 1) * 16 + px_l;
      unsigned lo = (unsigned)f2bf(fmaxf(acc[t][0], 0.f)) |
                    ((unsigned)f2bf(fmaxf(acc[t][1], 0.f)) << 16);
      unsigned hi = (unsigned)f2bf(fmaxf(acc[t][2], 0.f)) |
                    ((unsigned)f2bf(fmaxf(acc[t][3], 0.f)) << 16);
      *(uint2*)(x2out + ((size_t)b * HWW + (size_t)gy * WW + gx) * 16 + og * 4) = make_uint2(lo, hi);
    }
  } else {
    char* stage = smem;
    char* t3 = smem + 12 * 36 * 32;

    for (int i = tid; i < 12 * 36 * 2; i += 256) {
      int pp = i >> 1;
      int s = i & 1;
      int lr = pp / 36;
      int lc = pp - lr * 36;
      int gy = ty0 + lr - 2;
      int gx = tx0 + lc - 2;
      uint4 v = make_uint4(0, 0, 0, 0);
      if (gy >= 0 && gy < HH && gx >= 0 && gx < WW)
        v = *(const uint4*)(xt + ((size_t)b * HWW + (size_t)gy * WW + gx) * 16 + s * 8);
      int swz = (s ^ (pp >> 2)) & 1;
      *(uint4*)(stage + (size_t)pp * 32 + (swz << 4)) = v;
    }
    __syncthreads();

    {
      bf16x8 afr1[5];
#pragma unroll
      for (int s = 0; s < 5; ++s)
        afr1[s] = *(const bf16x8*)(w2m + (size_t)((s * 64 + lane) * 8));
      f32x4 bvec;
#pragma unroll
      for (int r = 0; r < 4; ++r) bvec[r] = b2[og * 4 + r];
      int tap1[5], slot1[5];
#pragma unroll
      for (int s = 0; s < 5; ++s) {
        int klin = s * 32 + og * 8;
        int tap = klin / 16;
        if (tap > 8) tap = 8;
        int coff = klin % 16;
        tap1[s] = (tap / 3) * 36 + (tap % 3);
        slot1[s] = coff >> 3;
      }
      for (int f = wv; f < 22; f += 4) {
        int p = f * 16 + px_l;
        int r = p / 34;
        int c = p - r * 34;
        f32x4 acc = bvec;
#pragma unroll
        for (int s = 0; s < 5; ++s) {
          int pp2 = r * 36 + c + tap1[s];
          int off = pp2 * 32 + (((slot1[s] ^ (pp2 >> 2)) & 1) << 4);
          bf16x8 bv = *(const bf16x8*)(stage + off);
          acc = __builtin_amdgcn_mfma_f32_16x16x32_bf16(afr1[s], bv, acc, 0, 0, 0);
        }
        if (p < 340) {
          int gy = ty0 + r - 1;
          int gx = tx0 + c - 1;
          unsigned lo = 0, hi = 0;
          if (gy >= 0 && gy < HH && gx >= 0 && gx < WW) {
            lo = (unsigned)f2bf(fmaxf(acc[0], 0.f)) | ((unsigned)f2bf(fmaxf(acc[1], 0.f)) << 16);
            hi = (unsigned)f2bf(fmaxf(acc[2], 0.f)) | ((unsigned)f2bf(fmaxf(acc[3], 0.f)) << 16);
          }
          int slot = og >> 1;
          int off = p * 32 + (((slot ^ (p >> 2)) & 1) << 4) + (og & 1) * 8;
          *(uint2*)(t3 + off) = make_uint2(lo, hi);
        }
      }
    }
    __syncthreads();

    bf16x8 afr2[2][5];
#pragma unroll
    for (int ot = 0; ot < 2; ++ot)
#pragma unroll
      for (int s = 0; s < 5; ++s)
        afr2[ot][s] = *(const bf16x8*)(w3m + (size_t)(((ot * 5 + s) * 64 + lane) * 8));

    f32x4 acc2[4][2];
#pragma unroll
    for (int ot = 0; ot < 2; ++ot) {
      f32x4 bv;
#pragma unroll
      for (int r = 0; r < 4; ++r) {
        int o = ot * 16 + og * 4 + r;
        bv[r] = b3[o < 27 ? o : 26];
      }
#pragma unroll
      for (int t = 0; t < 4; ++t) acc2[t][ot] = bv;
    }

    int tap2[5], slot2[5];
#pragma unroll
    for (int s = 0; s < 5; ++s) {
      int klin = s * 32 + og * 8;
      int tap = klin / 16;
      if (tap > 8) tap = 8;
      int coff = klin % 16;
      tap2[s] = (tap / 3) * 34 + (tap % 3);
      slot2[s] = coff >> 3;
    }

    const int oy_l = wv * 2;
#pragma unroll
    for (int t = 0; t < 4; ++t) {
      const int base_pix = (oy_l + (t >> 1)) * 34 + (t & 1) * 16 + px_l;
#pragma unroll
      for (int s = 0; s < 5; ++s) {
        int pp = base_pix + tap2[s];
        int off = pp * 32 + (((slot2[s] ^ (pp >> 2)) & 1) << 4);
        bf16x8 bv = *(const bf16x8*)(t3 + off);
        acc2[t][0] = __builtin_amdgcn_mfma_f32_16x16x32_bf16(afr2[0][s], bv, acc2[t][0], 0, 0, 0);
        acc2[t][1] = __builtin_amdgcn_mfma_f32_16x16x32_bf16(afr2[1][s], bv, acc2[t][1], 0, 0, 0);
      }
    }

#pragma unroll
    for (int t = 0; t < 4; ++t) {
      const int gy = ty0 + oy_l + (t >> 1);
      const int gx = tx0 + (t & 1) * 16 + px_l;
      unsigned short* dst = omb + ((size_t)b * HWW + (size_t)gy * WW + gx) * 32;
#pragma unroll
      for (int ot = 0; ot < 2; ++ot) {
        const int o0 = ot * 16 + og * 4;
        unsigned lo = (unsigned)f2bf(acc2[t][ot][0]) | ((unsigned)f2bf(acc2[t][ot][1]) << 16);
        unsigned hi = (unsigned)f2bf(acc2[t][ot][2]) | ((unsigned)f2bf(acc2[t][ot][3]) << 16);
        *(uint2*)(dst + o0) = make_uint2(lo, hi);
      }
    }
  }
}

// ---------------------------------------------------------------------------
// Modulated deformable conv v6 (unchanged round 12): om padded NHWC, phase-A
// address precompute, __launch_bounds__(256,4).
// ---------------------------------------------------------------------------
__global__ __launch_bounds__(256, 4) void deform_v6(
    const unsigned short* __restrict__ xn, const unsigned short* __restrict__ om32,
    const float* __restrict__ wt, const float* __restrict__ bias,
    unsigned short* __restrict__ out) {
  const int bid = blockIdx.x;
  const int xcd = bid & 7;
  const int b = xcd >> 1;
  const int pb = ((bid >> 3) << 1) | (xcd & 1);
  const int pixel = pb * 256 + (int)threadIdx.x;
  const int y = pixel >> 8;
  const int xq = pixel & 255;
  const unsigned short* xb = xn + (size_t)b * HWW * 16;

  const uint4* omp = (const uint4*)(om32 + ((size_t)b * HWW + pixel) * 32);
  uint4 q0 = omp[0], q1 = omp[1], q2 = omp[2], q3 = omp[3];
  unsigned ow[14] = {q0.x, q0.y, q0.z, q0.w, q1.x, q1.y, q1.z, q1.w,
                     q2.x, q2.y, q2.z, q2.w, q3.x, q3.y};

  int i00[9], i01[9], i10[9], i11[9];
  float w00[9], w01[9], w10[9], w11[9];
#pragma unroll
  for (int k = 0; k < 9; ++k) {
    unsigned wy_ = ow[(2 * k) >> 1];
    float offy = ((2 * k) & 1) ? bf_hi(wy_) : bf_lo(wy_);
    unsigned wx_ = ow[(2 * k + 1) >> 1];
    float offx = ((2 * k + 1) & 1) ? bf_hi(wx_) : bf_lo(wx_);
    unsigned wm_ = ow[(18 + k) >> 1];
    float mr = ((18 + k) & 1) ? bf_hi(wm_) : bf_lo(wm_);
    float m = 1.0f / (1.0f + expf(-mr));
    float py = (float)y + (float)(k / 3 - 1) + offy;
    float px = (float)xq + (float)(k % 3 - 1) + offx;
    float y0f = floorf(py);
    float x0f = floorf(px);
    float dy = py - y0f;
    float dx = px - x0f;
    int y0 = (int)y0f, x0 = (int)x0f;
    int y1 = y0 + 1, x1 = x0 + 1;
    bool vy0 = (y0 >= 0) && (y0 < HH);
    bool vy1 = (y1 >= 0) && (y1 < HH);
    bool vx0 = (x0 >= 0) && (x0 < WW);
    bool vx1 = (x1 >= 0) && (x1 < WW);
    int yc0 = min(max(y0, 0), HH - 1);
    int yc1 = min(max(y1, 0), HH - 1);
    int xc0 = min(max(x0, 0), WW - 1);
    int xc1 = min(max(x1, 0), WW - 1);
    float a00 = (1.f - dy) * (1.f - dx) * m;
    float a01 = (1.f - dy) * dx * m;
    float a10 = dy * (1.f - dx) * m;
    float a11 = dy * dx * m;
    if (!(vy0 && vx0)) a00 = 0.f;
    if (!(vy0 && vx1)) a01 = 0.f;
    if (!(vy1 && vx0)) a10 = 0.f;
    if (!(vy1 && vx1)) a11 = 0.f;
    w00[k] = a00; w01[k] = a01; w10[k] = a10; w11[k] = a11;
    i00[k] = yc0 * WW + xc0;
    i01[k] = yc0 * WW + xc1;
    i10[k] = yc1 * WW + xc0;
    i11[k] = yc1 * WW + xc1;
  }

  float acc[16];
#pragma unroll
  for (int o = 0; o < 16; ++o) acc[o] = bias[o];

#pragma unroll
  for (int k = 0; k < 9; ++k) {
    const uint4* p00 = (const uint4*)(xb + (size_t)i00[k] * 16);
    const uint4* p01 = (const uint4*)(xb + (size_t)i01[k] * 16);
    const uint4* p10 = (const uint4*)(xb + (size_t)i10[k] * 16);
    const uint4* p11 = (const uint4*)(xb + (size_t)i11[k] * 16);
    uint4 a0 = p00[0], a1 = p00[1];
    uint4 b0 = p01[0], b1 = p01[1];
    uint4 c0 = p10[0], c1 = p10[1];
    uint4 d0 = p11[0], d1 = p11[1];
    unsigned wA[8] = {a0.x, a0.y, a0.z, a0.w, a1.x, a1.y, a1.z, a1.w};
    unsigned wB[8] = {b0.x, b0.y, b0.z, b0.w, b1.x, b1.y, b1.z, b1.w};
    unsigned wC[8] = {c0.x, c0.y, c0.z, c0.w, c1.x, c1.y, c1.z, c1.w};
    unsigned wD[8] = {d0.x, d0.y, d0.z, d0.w, d1.x, d1.y, d1.z, d1.w};

    float s[16];
#pragma unroll
    for (int j = 0; j < 8; ++j) {
      s[2 * j]     = bf_lo(wA[j]) * w00[k] + bf_lo(wB[j]) * w01[k] + bf_lo(wC[j]) * w10[k] + bf_lo(wD[j]) * w11[k];
      s[2 * j + 1] = bf_hi(wA[j]) * w00[k] + bf_hi(wB[j]) * w01[k] + bf_hi(wC[j]) * w10[k] + bf_hi(wD[j]) * w11[k];
    }
    const float* wk = wt + (size_t)k * 256;
#pragma unroll
    for (int c = 0; c < 16; ++c)
#pragma unroll
      for (int o = 0; o < 16; ++o)
        acc[o] = fmaf(s[c], wk[c * 16 + o], acc[o]);
  }
  unsigned r[8];
#pragma unroll
  for (int j = 0; j < 8; ++j) {
    unsigned short lo = f2bf(fmaxf(acc[2 * j], 0.f));
    unsigned short hi = f2bf(fmaxf(acc[2 * j + 1], 0.f));
    r[j] = (unsigned)lo | ((unsigned)hi << 16);
  }
  uint4* d4 = (uint4*)(out + ((size_t)b * HWW + pixel) * 16);
  d4[0] = make_uint4(r[0], r[1], r[2], r[3]);
  d4[1] = make_uint4(r[4], r[5], r[6], r[7]);
}

// ---------------------------------------------------------------------------
// Fused K8+K9 (fin_fused): unchanged from round 9.
// ---------------------------------------------------------------------------
__global__ __launch_bounds__(256) void fin_fused_k(
    const unsigned short* __restrict__ xsa, const unsigned short* __restrict__ xf,
    const unsigned short* __restrict__ wdm, const float* __restrict__ bd,
    const unsigned short* __restrict__ x2,
    const unsigned short* __restrict__ wfm, const float* __restrict__ bfv,
    float* __restrict__ outp) {
  __shared__ __align__(16) char smem[12 * 36 * 64 + 10 * 34 * 32];
  char* stage = smem;
  char* dtile = smem + 12 * 36 * 64;
  char* x2tile = smem;

  const int b = blockIdx.z;
  const int tx0 = blockIdx.x * 32;
  const int ty0 = blockIdx.y * 8;
  const int tid = threadIdx.x;
  const int lane = tid & 63;
  const int wv = tid >> 6;
  const int px_l = lane & 15;
  const int og = lane >> 4;

  for (int i = tid; i < 12 * 36 * 4; i += 256) {
    int pp = i >> 2;
    int s = i & 3;
    int lr = pp / 36;
    int lc = pp - lr * 36;
    int gy = ty0 + lr - 2;
    int gx = tx0 + lc - 2;
    uint4 v = make_uint4(0, 0, 0, 0);
    if (gy >= 0 && gy < HH && gx >= 0 && gx < WW) {
      const unsigned short* src = (s < 2) ? xsa : xf;
      int sl = (s >= 2) ? s - 2 : s;
      v = *(const uint4*)(src + ((size_t)b * HWW + (size_t)gy * WW + gx) * 16 + sl * 8);
    }
    int swz = (s ^ (pp >> 1)) & 3;
    *(uint4*)(stage + (size_t)pp * 64 + (swz << 4)) = v;
  }
  __syncthreads();

  {
    bf16x8 afr1[9];
#pragma unroll
    for (int s = 0; s < 9; ++s)
      afr1[s] = *(const bf16x8*)(wdm + (size_t)((s * 64 + lane) * 8));
    f32x4 bvec;
#pragma unroll
    for (int r = 0; r < 4; ++r) bvec[r] = bd[og * 4 + r];
    int tap1[9], slot1[9];
#pragma unroll
    for (int s = 0; s < 9; ++s) {
      int klin = s * 32 + og * 8;
      int tap = klin / 32;
      int coff = klin % 32;
      tap1[s] = (tap / 3) * 36 + (tap % 3);
      slot1[s] = coff >> 3;
    }
    for (int f = wv; f < 22; f += 4) {
      int p = f * 16 + px_l;
      int r = p / 34;
      int c = p - r * 34;
      f32x4 acc = bvec;
#pragma unroll
      for (int s = 0; s < 9; ++s) {
        int pp2 = r * 36 + c + tap1[s];
        int off = pp2 * 64 + (((slot1[s] ^ (pp2 >> 1)) & 3) << 4);
        bf16x8 bv = *(const bf16x8*)(stage + off);
        acc = __builtin_amdgcn_mfma_f32_16x16x32_bf16(afr1[s], bv, acc, 0, 0, 0);
      }
      if (p < 340) {
        int gy = ty0 + r - 1;
        int gx = tx0 + c - 1;
        unsigned lo = 0, hi = 0;
        if (gy >= 0 && gy < HH && gx >= 0 && gx < WW) {
          lo = (unsigned)f2bf(fmaxf(acc[0], 0.f)) | ((unsigned)f2bf(fmaxf(acc[1], 0.f)) << 16);
          hi = (unsigned)f2bf(fmaxf(acc[2], 0.f)) | ((unsigned)f2bf(fmaxf(acc[3], 0.f)) << 16);
        }
        int slot = og >> 1;
        int off = p * 32 + (((slot ^ (p >> 2)) & 1) << 4) + (og & 1) * 8;
        *(uint2*)(dtile + off) = make_uint2(lo, hi);
      }
    }
  }
  __syncthreads();

  for (int i = tid; i < 340 * 2; i += 256) {
    int pp = i >> 1;
    int s = i & 1;
    int r = pp / 34;
    int c = pp - r * 34;
    int gy = ty0 + r - 1;
    int gx = tx0 + c - 1;
    uint4 v = make_uint4(0, 0, 0, 0);
    if (gy >= 0 && gy < HH && gx >= 0 && gx < WW)
      v = *(const uint4*)(x2 + ((size_t)b * HWW + (size_t)gy * WW + gx) * 16 + s * 8);
    int swz = (s ^ (pp >> 2)) & 1;
    *(uint4*)(x2tile + (size_t)pp * 32 + (swz << 4)) = v;
  }
  __syncthreads();

  bf16x8 afr2[9];
#pragma unroll
  for (int s = 0; s < 9; ++s)
    afr2[s] = *(const bf16x8*)(wfm + (size_t)((s * 64 + lane) * 8));

  f32x4 acc2[4];
  {
    f32x4 bv;
#pragma unroll
    for (int r = 0; r < 4; ++r) bv[r] = bfv[og * 4 + r];
#pragma unroll
    for (int t = 0; t < 4; ++t) acc2[t] = bv;
  }

  int tap2[9], slot2[9];
#pragma unroll
  for (int s = 0; s < 9; ++s) {
    int klin = s * 32 + og * 8;
    int tap = klin / 32;
    int coff = klin % 32;
    tap2[s] = (tap / 3) * 34 + (tap % 3);
    slot2[s] = coff >> 3;
  }

  const int oy_l = wv * 2;
#pragma unroll
  for (int t = 0; t < 4; ++t) {
    const int base_pix = (oy_l + (t >> 1)) * 34 + (t & 1) * 16 + px_l;
#pragma unroll
    for (int s = 0; s < 9; ++s) {
      int pp = base_pix + tap2[s];
      const char* basep = (slot2[s] < 2) ? x2tile : dtile;
      int sl = slot2[s] & 1;
      int off = pp * 32 + (((sl ^ (pp >> 2)) & 1) << 4);
      bf16x8 bv = *(const bf16x8*)(basep + off);
      acc2[t] = __builtin_amdgcn_mfma_f32_16x16x32_bf16(afr2[s], bv, acc2[t], 0, 0, 0);
    }
  }

#pragma unroll
  for (int t = 0; t < 4; ++t) {
    const int gy = ty0 + oy_l + (t >> 1);
    const int gx = tx0 + (t & 1) * 16 + px_l;
    const int o0 = og * 4;
#pragma unroll
    for (int r = 0; r < 4; ++r)
      outp[((size_t)b * 16 + o0 + r) * HWW + (size_t)gy * WW + gx] = fmaxf(acc2[t][r], 0.f);
  }
}

extern "C" void kernel_launch(void* const* d_in, const int* in_sizes, int n_in,
                              void* d_out, int out_size, void* d_ws, size_t ws_size,
                              hipStream_t stream) {
  (void)in_sizes; (void)n_in; (void)out_size; (void)ws_size;
  const float* f_E = (const float*)d_in[0];
  const float* f_F = (const float*)d_in[1];
  const float* att_w1 = (const float*)d_in[2];
  const float* att_b1 = (const float*)d_in[3];
  const float* att_w2 = (const float*)d_in[4];
  const float* att_b2 = (const float*)d_in[5];
  const float* ref_w = (const float*)d_in[6];
  const float* ref_b = (const float*)d_in[7];
  const float* om_w1 = (const float*)d_in[8];
  const float* om_b1 = (const float*)d_in[9];
  const float* om_w2 = (const float*)d_in[10];
  const float* om_b2 = (const float*)d_in[11];
  const float* om_w3 = (const float*)d_in[12];
  const float* om_b3 = (const float*)d_in[13];
  const float* dcb_w = (const float*)d_in[14];
  const float* dcb_b = (const float*)d_in[15];
  const float* dcbref_w = (const float*)d_in[16];
  const float* dcbref_b = (const float*)d_in[17];
  const float* fin_w = (const float*)d_in[18];
  const float* fin_b = (const float*)d_in[19];
  float* outp = (float*)d_out;

  const size_t TN = (size_t)4 * HWW * 16;            // bf16 NHWC tensor elems
  unsigned short* XE  = (unsigned short*)d_ws;       // f_E
  unsigned short* XF  = XE + TN;                     // f_F
  unsigned short* XA  = XF + TN;                     // conv_a
  unsigned short* XT  = XA + TN;                     // om_t2
  unsigned short* X2  = XT + TN;                     // f_EFsa
  unsigned short* XSA = X2 + TN;                     // f_Edc
  unsigned short* OMB = XSA + TN;                    // om bf16 NHWC [pixel][32]
  unsigned short* WM  = OMB + (size_t)4 * HWW * 32;

  unsigned short* WM_att1 = WM;                 // CIN32 OT1: 4608 ush
  unsigned short* WM_ref  = WM_att1 + 4608;
  unsigned short* WM_om1  = WM_ref + 4608;
  unsigned short* WM_om2  = WM_om1 + 4608;      // CIN16 OT1: 2560
  unsigned short* WM_om3  = WM_om2 + 2560;      // CIN16 OT2: 5120
  unsigned short* WM_dref = WM_om3 + 5120;
  unsigned short* WM_fin  = WM_dref + 4608;
  float* WF_att2 = (float*)(WM_fin + 4608);     // mode0: 144 f
  float* WF_dcb  = WF_att2 + 144;               // mode1: 2304 f

  RA ra;
  ra.d[0] = {att_w1, WM_att1, 32, 16, 2};
  ra.d[1] = {ref_w, WM_ref, 32, 16, 2};
  ra.d[2] = {om_w1, WM_om1, 32, 16, 2};
  ra.d[3] = {om_w2, WM_om2, 16, 16, 2};
  ra.d[4] = {om_w3, WM_om3, 16, 27, 2};
  ra.d[5] = {dcbref_w, WM_dref, 32, 16, 2};
  ra.d[6] = {fin_w, WM_fin, 32, 16, 2};
  ra.d[7] = {att_w2, WF_att2, 16, 1, 0};
  ra.d[8] = {dcb_w, WF_dcb, 16, 16, 1};

  dim3 blk(256);
  repack_k<<<dim3(9), blk, 0, stream>>>(ra);

  dim3 gm(WW / 32, HH / 8, 4);   // 1024 blocks

  // prep+K1+K4: XE, XF, conv_a, om_t2 in one pass
  conv_dual2_k<<<gm, blk, 0, stream>>>(f_E, f_F, WM_att1, att_b1, WM_om1, om_b1,
                                       XE, XF, XA, XT);
  // K2+K3 (even blocks) || K5+K6 (odd blocks); om -> padded NHWC
  mid_k<<<dim3(2048), blk, 0, stream>>>(XA, XE, XF, WF_att2, att_b2, WM_ref, ref_b, X2,
                                        XT, WM_om2, om_b2, WM_om3, om_b3, OMB);
  // K7: f_Edc
  deform_v6<<<dim3(1024), blk, 0, stream>>>(XE, OMB, WF_dcb, dcb_b, XSA);
  // K8+K9: out
  fin_fused_k<<<gm, blk, 0, stream>>>(XSA, XF, WM_dref, dcbref_b, X2, WM_fin, fin_b, outp);
}